// Round 1
// baseline (30.880 us; speedup 1.0000x reference)
//
#include <hip/hip_runtime.h>

// SpanRepresentation: B=16, L=128, D=768, W=128, SPAN_MAX_LEN=8 -> n_spans=996
// spans: (B, 996, 1664) f32 ; span_indices: (996, 2) written as float values
// appended flat after spans.

#define LSEQ   128
#define DDIM   768
#define WDIM   128
#define NSPANS 996
#define ROW    1664   // 2*D + W
#define ROW4   416    // ROW/4

__device__ __forceinline__ void decode_span(int s, int& start, int& end, int& bucket) {
    // width-major groups; group g (w=g) has 129-g spans
    int w = 1, base = 0;
    if (s >= 128) { w = 2; base = 128; }
    if (s >= 255) { w = 3; base = 255; }
    if (s >= 381) { w = 4; base = 381; }
    if (s >= 506) { w = 5; base = 506; }
    if (s >= 630) { w = 6; base = 630; }
    if (s >= 753) { w = 7; base = 753; }
    if (s >= 875) { w = 8; base = 875; }
    start  = s - base;
    end    = start + w - 1;
    bucket = w - (w >= 6 ? 1 : 0);   // widths 1..8 -> buckets 1,2,3,4,5,5,6,7
}

__global__ void span_rep_kernel(const float* __restrict__ x,
                                const float* __restrict__ we,
                                float* __restrict__ out,
                                int B) {
    const int total4 = B * NSPANS * ROW4;
    const int stride = gridDim.x * blockDim.x;
    for (int i = blockIdx.x * blockDim.x + threadIdx.x; i < total4; i += stride) {
        int b   = i / (NSPANS * ROW4);
        int rem = i - b * (NSPANS * ROW4);
        int s   = rem / ROW4;
        int c4  = rem - s * ROW4;
        int c   = c4 * 4;

        int start, end, bucket;
        decode_span(s, start, end, bucket);

        float4 v;
        if (c < DDIM) {
            v = *reinterpret_cast<const float4*>(
                    &x[((long)b * LSEQ + start) * DDIM + c]);
        } else if (c < 2 * DDIM) {
            v = *reinterpret_cast<const float4*>(
                    &x[((long)b * LSEQ + end) * DDIM + (c - DDIM)]);
        } else {
            v = *reinterpret_cast<const float4*>(
                    &we[bucket * WDIM + (c - 2 * DDIM)]);
        }
        *reinterpret_cast<float4*>(&out[(long)i * 4]) = v;
    }
}

__global__ void span_idx_kernel(float* __restrict__ out_idx) {
    int s = blockIdx.x * blockDim.x + threadIdx.x;
    if (s >= NSPANS) return;
    int start, end, bucket;
    decode_span(s, start, end, bucket);
    out_idx[2 * s + 0] = (float)start;
    out_idx[2 * s + 1] = (float)end;
}

extern "C" void kernel_launch(void* const* d_in, const int* in_sizes, int n_in,
                              void* d_out, int out_size, void* d_ws, size_t ws_size,
                              hipStream_t stream) {
    const float* x  = (const float*)d_in[0];
    const float* we = (const float*)d_in[1];
    float* out = (float*)d_out;

    int B = in_sizes[0] / (LSEQ * DDIM);   // 16

    const int block = 256;
    const int total4 = B * NSPANS * ROW4;
    int grid = (total4 + block - 1) / block;
    if (grid > 2048) grid = 2048;          // grid-stride, ~8 blocks/CU
    span_rep_kernel<<<grid, block, 0, stream>>>(x, we, out, B);

    float* out_idx = out + (long)B * NSPANS * ROW;
    span_idx_kernel<<<(NSPANS + block - 1) / block, block, 0, stream>>>(out_idx);
}

// Round 2
// 25.293 us; speedup vs baseline: 1.2209x; 1.2209x over previous
//
#include <hip/hip_runtime.h>

// SpanRepresentation: B=16, L=128, D=768, W=128, SPAN_MAX_LEN=8 -> n_spans=996
// out = spans (B,996,1664) f32  ++  span_indices (996,2) as float, flat.

#define LSEQ   128
#define DDIM   768
#define WDIM   128
#define NSPANS 996
#define ROW    1664   // 2*D + W
#define ROW4   416    // ROW/4
#define IDX4   498    // (996*2)/4 float4s of index tail

typedef float f4 __attribute__((ext_vector_type(4)));

__device__ __forceinline__ void decode_span(int s, int& start, int& end, int& bucket) {
    // width-major groups; group for width w has 129-w spans
    int w = 1, base = 0;
    if (s >= 128) { w = 2; base = 128; }
    if (s >= 255) { w = 3; base = 255; }
    if (s >= 381) { w = 4; base = 381; }
    if (s >= 506) { w = 5; base = 506; }
    if (s >= 630) { w = 6; base = 630; }
    if (s >= 753) { w = 7; base = 753; }
    if (s >= 875) { w = 8; base = 875; }
    start  = s - base;
    end    = start + w - 1;
    bucket = w - (w >= 6 ? 1 : 0);   // widths 1..8 -> buckets 1,2,3,4,5,5,6,7
}

__global__ __launch_bounds__(256) void span_rep_kernel(
        const float* __restrict__ x,
        const float* __restrict__ we,
        float* __restrict__ out,
        int B) {
    const int spans4 = B * NSPANS * ROW4;
    int i = blockIdx.x * 256 + threadIdx.x;

    if (i < spans4) {
        int b   = i / (NSPANS * ROW4);
        int rem = i - b * (NSPANS * ROW4);
        int s   = rem / ROW4;
        int c4  = rem - s * ROW4;
        int c   = c4 * 4;

        int start, end, bucket;
        decode_span(s, start, end, bucket);

        f4 v;
        if (c < DDIM) {
            v = *reinterpret_cast<const f4*>(
                    &x[((long)b * LSEQ + start) * DDIM + c]);
        } else if (c < 2 * DDIM) {
            v = *reinterpret_cast<const f4*>(
                    &x[((long)b * LSEQ + end) * DDIM + (c - DDIM)]);
        } else {
            v = *reinterpret_cast<const f4*>(
                    &we[bucket * WDIM + (c - 2 * DDIM)]);
        }
        __builtin_nontemporal_store(v, reinterpret_cast<f4*>(&out[(long)i * 4]));
    } else if (i < spans4 + IDX4) {
        int k = i - spans4;           // float4 index in tail; covers spans 2k, 2k+1
        int s0 = 2 * k, s1 = 2 * k + 1;
        int st0, en0, bk0, st1, en1, bk1;
        decode_span(s0, st0, en0, bk0);
        decode_span(s1, st1, en1, bk1);
        f4 v = { (float)st0, (float)en0, (float)st1, (float)en1 };
        __builtin_nontemporal_store(v,
            reinterpret_cast<f4*>(&out[(long)spans4 * 4 + (long)k * 4]));
    }
}

extern "C" void kernel_launch(void* const* d_in, const int* in_sizes, int n_in,
                              void* d_out, int out_size, void* d_ws, size_t ws_size,
                              hipStream_t stream) {
    const float* x  = (const float*)d_in[0];
    const float* we = (const float*)d_in[1];
    float* out = (float*)d_out;

    int B = in_sizes[0] / (LSEQ * DDIM);   // 16

    const int total4 = B * NSPANS * ROW4 + IDX4;
    const int block = 256;
    const int grid = (total4 + block - 1) / block;   // exact grid, no stride loop
    span_rep_kernel<<<grid, block, 0, stream>>>(x, we, out, B);
}

// Round 3
// 22.908 us; speedup vs baseline: 1.3480x; 1.1041x over previous
//
#include <hip/hip_runtime.h>

// SpanRepresentation: B=16, L=128, D=768, W=128, SPAN_MAX_LEN=8 -> n_spans=996
// out = spans (B,996,1664) f32 ++ span_indices (996,2) as float, flat.
//
// XCD-partitioned mapping: blockIdx % 8 (assumed XCD round-robin) selects a
// 2-batch slab, so each XCD's L2 holds only 2 batches of x (0.79 MB << 4 MiB)
// -> gather reads are XCD-local L2 hits; fabric carries only the write stream.

#define LSEQ    128
#define DDIM    768
#define WDIM    128
#define NSPANS  996
#define ROW     1664            // 2*D + W
#define ROW4    416             // ROW/4
#define PER_B4  (NSPANS * ROW4) // 414336 float4s per batch
#define IDX4    498             // (996*2)/4 float4s of index tail
#define NWG_MAIN 25896          // 16 * PER_B4 / 256 (exact, %8 == 0)

typedef float f4 __attribute__((ext_vector_type(4)));

__device__ __forceinline__ void decode_span(int s, int& start, int& end, int& bucket) {
    int w = 1, base = 0;
    if (s >= 128) { w = 2; base = 128; }
    if (s >= 255) { w = 3; base = 255; }
    if (s >= 381) { w = 4; base = 381; }
    if (s >= 506) { w = 5; base = 506; }
    if (s >= 630) { w = 6; base = 630; }
    if (s >= 753) { w = 7; base = 753; }
    if (s >= 875) { w = 8; base = 875; }
    start  = s - base;
    end    = start + w - 1;
    bucket = w - (w >= 6 ? 1 : 0);   // widths 1..8 -> buckets 1,2,3,4,5,5,6,7
}

__global__ __launch_bounds__(256) void span_rep_kernel(
        const float* __restrict__ x,
        const float* __restrict__ we,
        float* __restrict__ out) {
    const int wg = blockIdx.x;

    if (wg < NWG_MAIN) {
        const int xcd = wg & 7;
        const int j   = wg >> 3;
        const int idx = j * 256 + threadIdx.x;        // [0, 2*PER_B4)
        const int half = (idx >= PER_B4) ? 1 : 0;
        const int b    = 2 * xcd + half;
        const int rem  = idx - half * PER_B4;         // [0, PER_B4)
        const int s    = rem / ROW4;
        const int c4   = rem - s * ROW4;
        const int c    = c4 * 4;

        int start, end, bucket;
        decode_span(s, start, end, bucket);

        f4 v;
        if (c < DDIM) {
            v = *reinterpret_cast<const f4*>(
                    &x[((long)b * LSEQ + start) * DDIM + c]);
        } else if (c < 2 * DDIM) {
            v = *reinterpret_cast<const f4*>(
                    &x[((long)b * LSEQ + end) * DDIM + (c - DDIM)]);
        } else {
            v = *reinterpret_cast<const f4*>(
                    &we[bucket * WDIM + (c - 2 * DDIM)]);
        }
        const long i = (long)b * PER_B4 + rem;        // global float4 index
        __builtin_nontemporal_store(v, reinterpret_cast<f4*>(&out[i * 4]));
    } else {
        const int k = (wg - NWG_MAIN) * 256 + threadIdx.x;  // tail float4 index
        if (k < IDX4) {
            int s0 = 2 * k, s1 = 2 * k + 1;
            int st0, en0, bk0, st1, en1, bk1;
            decode_span(s0, st0, en0, bk0);
            decode_span(s1, st1, en1, bk1);
            f4 v = { (float)st0, (float)en0, (float)st1, (float)en1 };
            __builtin_nontemporal_store(v,
                reinterpret_cast<f4*>(&out[(long)NWG_MAIN * 1024 + (long)k * 4]));
        }
    }
}

extern "C" void kernel_launch(void* const* d_in, const int* in_sizes, int n_in,
                              void* d_out, int out_size, void* d_ws, size_t ws_size,
                              hipStream_t stream) {
    const float* x  = (const float*)d_in[0];
    const float* we = (const float*)d_in[1];
    float* out = (float*)d_out;

    const int grid = NWG_MAIN + 2;   // +2 blocks cover the 498-float4 index tail
    span_rep_kernel<<<grid, 256, 0, stream>>>(x, we, out);
}

// Round 4
// 22.547 us; speedup vs baseline: 1.3696x; 1.0160x over previous
//
#include <hip/hip_runtime.h>

// SpanRepresentation: B=16, L=128, D=768, W=128, SPAN_MAX_LEN=8 -> n_spans=996
// out = spans (B,996,1664) f32 ++ span_indices (996,2) as float, flat.
//
// XCD-partitioned mapping (R2): blockIdx%8 selects a 2-batch slab so gather
// reads stay XCD-L2-local. R3: plain stores (revert R1's nontemporal) — the
// 7 TB/s harness fill kernels use plain stores; L2 write-allocate is the
// write-combiner, nt bypass suspected of de-aggregating the write stream.

#define LSEQ    128
#define DDIM    768
#define WDIM    128
#define NSPANS  996
#define ROW     1664            // 2*D + W
#define ROW4    416             // ROW/4
#define PER_B4  (NSPANS * ROW4) // 414336 float4s per batch
#define IDX4    498             // (996*2)/4 float4s of index tail
#define NWG_MAIN 25896          // 16 * PER_B4 / 256 (exact, %8 == 0)

typedef float f4 __attribute__((ext_vector_type(4)));

__device__ __forceinline__ void decode_span(int s, int& start, int& end, int& bucket) {
    int w = 1, base = 0;
    if (s >= 128) { w = 2; base = 128; }
    if (s >= 255) { w = 3; base = 255; }
    if (s >= 381) { w = 4; base = 381; }
    if (s >= 506) { w = 5; base = 506; }
    if (s >= 630) { w = 6; base = 630; }
    if (s >= 753) { w = 7; base = 753; }
    if (s >= 875) { w = 8; base = 875; }
    start  = s - base;
    end    = start + w - 1;
    bucket = w - (w >= 6 ? 1 : 0);   // widths 1..8 -> buckets 1,2,3,4,5,5,6,7
}

__global__ __launch_bounds__(256) void span_rep_kernel(
        const float* __restrict__ x,
        const float* __restrict__ we,
        float* __restrict__ out) {
    const int wg = blockIdx.x;

    if (wg < NWG_MAIN) {
        const int xcd = wg & 7;
        const int j   = wg >> 3;
        const int idx = j * 256 + threadIdx.x;        // [0, 2*PER_B4)
        const int half = (idx >= PER_B4) ? 1 : 0;
        const int b    = 2 * xcd + half;
        const int rem  = idx - half * PER_B4;         // [0, PER_B4)
        const int s    = rem / ROW4;
        const int c4   = rem - s * ROW4;
        const int c    = c4 * 4;

        int start, end, bucket;
        decode_span(s, start, end, bucket);

        f4 v;
        if (c < DDIM) {
            v = *reinterpret_cast<const f4*>(
                    &x[((long)b * LSEQ + start) * DDIM + c]);
        } else if (c < 2 * DDIM) {
            v = *reinterpret_cast<const f4*>(
                    &x[((long)b * LSEQ + end) * DDIM + (c - DDIM)]);
        } else {
            v = *reinterpret_cast<const f4*>(
                    &we[bucket * WDIM + (c - 2 * DDIM)]);
        }
        const long i = (long)b * PER_B4 + rem;        // global float4 index
        *reinterpret_cast<f4*>(&out[i * 4]) = v;      // plain store (L2 write-combine)
    } else {
        const int k = (wg - NWG_MAIN) * 256 + threadIdx.x;  // tail float4 index
        if (k < IDX4) {
            int s0 = 2 * k, s1 = 2 * k + 1;
            int st0, en0, bk0, st1, en1, bk1;
            decode_span(s0, st0, en0, bk0);
            decode_span(s1, st1, en1, bk1);
            f4 v = { (float)st0, (float)en0, (float)st1, (float)en1 };
            *reinterpret_cast<f4*>(&out[(long)NWG_MAIN * 1024 + (long)k * 4]) = v;
        }
    }
}

extern "C" void kernel_launch(void* const* d_in, const int* in_sizes, int n_in,
                              void* d_out, int out_size, void* d_ws, size_t ws_size,
                              hipStream_t stream) {
    const float* x  = (const float*)d_in[0];
    const float* we = (const float*)d_in[1];
    float* out = (float*)d_out;

    const int grid = NWG_MAIN + 2;   // +2 blocks cover the 498-float4 index tail
    span_rep_kernel<<<grid, 256, 0, stream>>>(x, we, out);
}